// Round 1
// baseline (6916.656 us; speedup 1.0000x reference)
//
#include <hip/hip_runtime.h>
#include <math.h>

#define NWIN 8192
#define NROW 64
#define DIM  180
#define NH   6
#define HD   30
#define KD   16
#define NT   512

#define XS_STRIDE  65   // xsT [180][65]  (transposed x)
#define QKV_STRIDE 36   // q/k/v [64][36] row-major, cols 30..35 zero
#define DB_STRIDE  65   // dB [64][65]
#define P_STRIDE   65   // P  [64][65]
#define ATT_STRIDE 65   // attT [180][65] (transposed attention output)
#define BPE_STRIDE 20   // bpe [64][20]

#define OFF_XST 0
#define OFF_Q   (180*XS_STRIDE)            // 11700
#define OFF_K   (OFF_Q + 64*QKV_STRIDE)    // +2304
#define OFF_V   (OFF_K + 64*QKV_STRIDE)
#define OFF_DB  (OFF_V + 64*QKV_STRIDE)
#define OFF_P   (OFF_DB + 64*DB_STRIDE)
#define OFF_ATT (OFF_P + 64*P_STRIDE)
#define OFF_BPE (OFF_ATT + 180*ATT_STRIDE)
#define LDS_FLOATS (OFF_BPE + 64*BPE_STRIDE)   // 39912 floats = 159648 B

__device__ __forceinline__ float4 ld4(const float* p) {
    return *reinterpret_cast<const float4*>(p);
}
__device__ __forceinline__ void st4(float* p, float a, float b, float c, float d) {
    *reinterpret_cast<float4*>(p) = make_float4(a, b, c, d);
}

__global__ void __launch_bounds__(NT, 1)
waga_fused(const float* __restrict__ x,
           const float* __restrict__ bpe,
           const float* __restrict__ qkv_w,
           const float* __restrict__ qkv_b,
           const float* __restrict__ proj_w,
           const float* __restrict__ proj_b,
           const float* __restrict__ tau,
           float* __restrict__ out)
{
    extern __shared__ float lds[];
    const int b = blockIdx.x;
    const int t = threadIdx.x;

    float* xsT  = lds + OFF_XST;
    float* qs   = lds + OFF_Q;
    float* ks   = lds + OFF_K;
    float* vs   = lds + OFF_V;
    float* dBs  = lds + OFF_DB;
    float* Ps   = lds + OFF_P;
    float* attT = lds + OFF_ATT;
    float* bpes = lds + OFF_BPE;

    // ---- stage x (transposed into xsT[d][n]) ----
    const float* xw = x + (size_t)b * (NROW * DIM);
    for (int i = t; i < NROW * DIM / 4; i += NT) {
        const int n = i / 45, d4 = i % 45;   // 180/4 = 45 float4 per row
        float4 xv = ld4(xw + i * 4);
        xsT[(4 * d4 + 0) * XS_STRIDE + n] = xv.x;
        xsT[(4 * d4 + 1) * XS_STRIDE + n] = xv.y;
        xsT[(4 * d4 + 2) * XS_STRIDE + n] = xv.z;
        xsT[(4 * d4 + 3) * XS_STRIDE + n] = xv.w;
    }
    // ---- stage bpe ----
    const float* bw = bpe + (size_t)b * (NROW * KD);
    for (int i = t; i < NROW * KD / 4; i += NT) {
        const int n = i / 4, k4 = i % 4;
        float4 v = ld4(bw + i * 4);
        bpes[n * BPE_STRIDE + 4 * k4 + 0] = v.x;
        bpes[n * BPE_STRIDE + 4 * k4 + 1] = v.y;
        bpes[n * BPE_STRIDE + 4 * k4 + 2] = v.z;
        bpes[n * BPE_STRIDE + 4 * k4 + 3] = v.w;
    }
    // ---- zero head-dim pad cols 30..35 of q,k,v (read by padded b128 dots) ----
    for (int i = t; i < 64 * 6 * 3; i += NT) {
        const int which = i / (64 * 6);
        const int r = (i % (64 * 6)) / 6;
        const int c = HD + (i % 6);
        float* dst = (which == 0) ? qs : (which == 1) ? ks : vs;
        dst[r * QKV_STRIDE + c] = 0.f;
    }
    __syncthreads();

    // ---- dB[i][j] = ||bpe_i - bpe_j||_2  (strided 2x4 tiles) ----
    {
        const int ti = t >> 4, tj = t & 15;   // ti 0..31, tj 0..15
        float acc[2][4] = {{0.f,0.f,0.f,0.f},{0.f,0.f,0.f,0.f}};
        #pragma unroll
        for (int k4 = 0; k4 < KD / 4; ++k4) {
            float4 a0 = ld4(bpes + ti * BPE_STRIDE + 4 * k4);
            float4 a1 = ld4(bpes + (ti + 32) * BPE_STRIDE + 4 * k4);
            #pragma unroll
            for (int e = 0; e < 4; ++e) {
                float4 bb = ld4(bpes + (tj + 16 * e) * BPE_STRIDE + 4 * k4);
                float d;
                d = a0.x - bb.x; acc[0][e] += d * d;
                d = a0.y - bb.y; acc[0][e] += d * d;
                d = a0.z - bb.z; acc[0][e] += d * d;
                d = a0.w - bb.w; acc[0][e] += d * d;
                d = a1.x - bb.x; acc[1][e] += d * d;
                d = a1.y - bb.y; acc[1][e] += d * d;
                d = a1.z - bb.z; acc[1][e] += d * d;
                d = a1.w - bb.w; acc[1][e] += d * d;
            }
        }
        #pragma unroll
        for (int r = 0; r < 2; ++r)
            #pragma unroll
            for (int e = 0; e < 4; ++e)
                dBs[(ti + 32 * r) * DB_STRIDE + tj + 16 * e] = sqrtf(acc[r][e]);
    }
    __syncthreads();

    const float scale = 0.18257418583505536f;  // 30^-0.5

    for (int h = 0; h < NH; ++h) {
        // ---- qkv projection for head h: 90 channels, outer-product w/ broadcast w ----
        if (t < 480) {
            const int cg = t >> 5;        // 0..14 : channel group of 6
            const int nb = t & 31;        // rows {nb, nb+32}
            float acc0[6] = {0.f,0.f,0.f,0.f,0.f,0.f};
            float acc1[6] = {0.f,0.f,0.f,0.f,0.f,0.f};
            const float* wrow[6];
            int crow[6];
            #pragma unroll
            for (int i = 0; i < 6; ++i) {
                const int m = cg * 6 + i;           // 0..89
                const int which = m / HD, dd = m % HD;
                crow[i] = which * DIM + h * HD + dd;
                wrow[i] = qkv_w + (size_t)crow[i] * DIM;
            }
            for (int d4 = 0; d4 < DIM / 4; ++d4) {
                const int dbase = 4 * d4;
                float xa0 = xsT[(dbase + 0) * XS_STRIDE + nb];
                float xa1 = xsT[(dbase + 1) * XS_STRIDE + nb];
                float xa2 = xsT[(dbase + 2) * XS_STRIDE + nb];
                float xa3 = xsT[(dbase + 3) * XS_STRIDE + nb];
                float xb0 = xsT[(dbase + 0) * XS_STRIDE + nb + 32];
                float xb1 = xsT[(dbase + 1) * XS_STRIDE + nb + 32];
                float xb2 = xsT[(dbase + 2) * XS_STRIDE + nb + 32];
                float xb3 = xsT[(dbase + 3) * XS_STRIDE + nb + 32];
                #pragma unroll
                for (int i = 0; i < 6; ++i) {
                    float4 wv = ld4(wrow[i] + dbase);
                    acc0[i] += xa0 * wv.x + xa1 * wv.y + xa2 * wv.z + xa3 * wv.w;
                    acc1[i] += xb0 * wv.x + xb1 * wv.y + xb2 * wv.z + xb3 * wv.w;
                }
            }
            #pragma unroll
            for (int i = 0; i < 6; ++i) {
                const int m = cg * 6 + i;
                const int which = m / HD, dd = m % HD;
                const float bias = qkv_b[crow[i]];
                float v0 = acc0[i] + bias;
                float v1 = acc1[i] + bias;
                if (which == 0) { v0 *= scale; v1 *= scale; }  // fold SCALE into q
                float* dst = (which == 0) ? qs : (which == 1) ? ks : vs;
                dst[nb * QKV_STRIDE + dd] = v0;
                dst[(nb + 32) * QKV_STRIDE + dd] = v1;
            }
        }
        __syncthreads();

        // ---- S = q k^T + bias ; softmax -> P ----
        {
            const float inv_tau = 1.f / fmaxf(tau[h], 1e-6f);
            const int tn = t >> 4, tj = t & 15;  // rows {tn,tn+32}, cols {tj+16e}
            float acc[2][4] = {{0.f,0.f,0.f,0.f},{0.f,0.f,0.f,0.f}};
            #pragma unroll
            for (int d4 = 0; d4 < QKV_STRIDE / 4; ++d4) {   // 9 steps, pad cols are 0
                float4 qa = ld4(qs + tn * QKV_STRIDE + 4 * d4);
                float4 qb = ld4(qs + (tn + 32) * QKV_STRIDE + 4 * d4);
                #pragma unroll
                for (int e = 0; e < 4; ++e) {
                    float4 kk = ld4(ks + (tj + 16 * e) * QKV_STRIDE + 4 * d4);
                    acc[0][e] += qa.x * kk.x + qa.y * kk.y + qa.z * kk.z + qa.w * kk.w;
                    acc[1][e] += qb.x * kk.x + qb.y * kk.y + qb.z * kk.z + qb.w * kk.w;
                }
            }
            #pragma unroll
            for (int r = 0; r < 2; ++r) {
                const int row = tn + 32 * r;
                float s[4];
                #pragma unroll
                for (int e = 0; e < 4; ++e)
                    s[e] = acc[r][e] - dBs[row * DB_STRIDE + tj + 16 * e] * inv_tau;
                float m = fmaxf(fmaxf(s[0], s[1]), fmaxf(s[2], s[3]));
                #pragma unroll
                for (int o = 1; o < 16; o <<= 1) m = fmaxf(m, __shfl_xor(m, o, 16));
                float p[4], sum = 0.f;
                #pragma unroll
                for (int e = 0; e < 4; ++e) { p[e] = __expf(s[e] - m); sum += p[e]; }
                #pragma unroll
                for (int o = 1; o < 16; o <<= 1) sum += __shfl_xor(sum, o, 16);
                const float inv = 1.f / sum;
                #pragma unroll
                for (int e = 0; e < 4; ++e)
                    Ps[row * P_STRIDE + tj + 16 * e] = p[e] * inv;
            }
        }
        __syncthreads();

        // ---- PV -> attT (transposed) ----
        {
            const int n = t & 63, td = t >> 6;   // td 0..7 -> cols {4td..4td+3}
            float acc[4] = {0.f, 0.f, 0.f, 0.f};
            for (int j = 0; j < NROW; ++j) {
                const float p = Ps[n * P_STRIDE + j];
                float4 vv = ld4(vs + j * QKV_STRIDE + 4 * td);
                acc[0] += p * vv.x; acc[1] += p * vv.y;
                acc[2] += p * vv.z; acc[3] += p * vv.w;
            }
            #pragma unroll
            for (int e = 0; e < 4; ++e) {
                const int c = 4 * td + e;
                if (c < HD) attT[(h * HD + c) * ATT_STRIDE + n] = acc[e];
            }
        }
        __syncthreads();
    }

    // ---- output projection ----
    if (t < 480) {
        const int cg = t >> 5;   // 0..14 : 12 output channels each
        const int nb = t & 31;   // rows {nb, nb+32}
        float acc0[12] = {0,0,0,0,0,0,0,0,0,0,0,0};
        float acc1[12] = {0,0,0,0,0,0,0,0,0,0,0,0};
        for (int c4 = 0; c4 < DIM / 4; ++c4) {
            const int cb = 4 * c4;
            float a00 = attT[(cb + 0) * ATT_STRIDE + nb];
            float a01 = attT[(cb + 1) * ATT_STRIDE + nb];
            float a02 = attT[(cb + 2) * ATT_STRIDE + nb];
            float a03 = attT[(cb + 3) * ATT_STRIDE + nb];
            float a10 = attT[(cb + 0) * ATT_STRIDE + nb + 32];
            float a11 = attT[(cb + 1) * ATT_STRIDE + nb + 32];
            float a12 = attT[(cb + 2) * ATT_STRIDE + nb + 32];
            float a13 = attT[(cb + 3) * ATT_STRIDE + nb + 32];
            #pragma unroll
            for (int i = 0; i < 12; ++i) {
                float4 wv = ld4(proj_w + (size_t)(cg * 12 + i) * DIM + cb);
                acc0[i] += a00 * wv.x + a01 * wv.y + a02 * wv.z + a03 * wv.w;
                acc1[i] += a10 * wv.x + a11 * wv.y + a12 * wv.z + a13 * wv.w;
            }
        }
        float* o0 = out + ((size_t)b * NROW + nb) * DIM + cg * 12;
        float* o1 = out + ((size_t)b * NROW + nb + 32) * DIM + cg * 12;
        #pragma unroll
        for (int q4 = 0; q4 < 3; ++q4) {
            const float* pb = proj_b + cg * 12 + 4 * q4;
            st4(o0 + 4 * q4, acc0[4*q4+0] + pb[0], acc0[4*q4+1] + pb[1],
                             acc0[4*q4+2] + pb[2], acc0[4*q4+3] + pb[3]);
            st4(o1 + 4 * q4, acc1[4*q4+0] + pb[0], acc1[4*q4+1] + pb[1],
                             acc1[4*q4+2] + pb[2], acc1[4*q4+3] + pb[3]);
        }
    }
}

extern "C" void kernel_launch(void* const* d_in, const int* in_sizes, int n_in,
                              void* d_out, int out_size, void* d_ws, size_t ws_size,
                              hipStream_t stream) {
    (void)in_sizes; (void)n_in; (void)d_ws; (void)ws_size; (void)out_size;
    const float* x      = (const float*)d_in[0];
    const float* bpe    = (const float*)d_in[1];
    const float* qkv_w  = (const float*)d_in[2];
    const float* qkv_b  = (const float*)d_in[3];
    const float* proj_w = (const float*)d_in[4];
    const float* proj_b = (const float*)d_in[5];
    const float* tau    = (const float*)d_in[6];

    const size_t lds_bytes = (size_t)LDS_FLOATS * sizeof(float);  // 159648
    // >64KB dynamic LDS: opt in (idempotent, non-stream call; safe under capture)
    (void)hipFuncSetAttribute((const void*)waga_fused,
                              hipFuncAttributeMaxDynamicSharedMemorySize,
                              (int)lds_bytes);
    waga_fused<<<NWIN, NT, lds_bytes, stream>>>(x, bpe, qkv_w, qkv_b,
                                                proj_w, proj_b, tau,
                                                (float*)d_out);
}

// Round 2
// 841.899 us; speedup vs baseline: 8.2155x; 8.2155x over previous
//
#include <hip/hip_runtime.h>
#include <math.h>

typedef __attribute__((ext_vector_type(8))) short short8b;   // 8 bf16 = 4 VGPR
typedef __attribute__((ext_vector_type(4))) float f32x4;     // MFMA acc

#define NWIN 8192
#define NT   512
#define SCALE 0.18257418583505536f   // 30^-0.5

// ---- LDS layout (bytes) ----
#define XB_P 200      // xb / att: [64][200] bf16, cols 180..199 zero
#define QK_P 40       // q/k per head: [64][40] bf16, cols 30..39 zero
#define VT_P 72       // vT per head: [32][72] bf16 (rows 30,31 zero)
#define DB_P 65       // dB: [64][65] f32
#define S_P  65       // S:  [64][65] f32
#define PP_P 72       // P:  [64][72] bf16
#define OST_P 180     // out staging: [64][180] f32

#define OFF_XB  0                         // 25600 B (aliased by att)
#define OFF_Q   25600                     // 6*64*40*2 = 30720
#define OFF_K   56320                     // 30720
#define OFF_VT  87040                     // 6*32*72*2 = 27648
#define OFF_DB  114688                    // 16640
#define OFF_S   131328                    // 16640 (bpe [64][20] f32 aliases here)
#define OFF_P   147968                    // 9216
#define LDS_BYTES 157184                  // <= 163840
#define OFF_OST OFF_Q                     // 46080 B aliases q+k (dead by then)

#define WQ_ROWS 544
#define WK 192

__device__ __forceinline__ unsigned short f2bf(float f) {
    union { float f; unsigned int u; } v; v.f = f;
    unsigned int r = (v.u + 0x7FFFu + ((v.u >> 16) & 1u)) >> 16;
    return (unsigned short)r;
}

__global__ void prep_weights(const float* __restrict__ qkv_w,
                             const float* __restrict__ proj_w,
                             unsigned short* __restrict__ wq,
                             unsigned short* __restrict__ wp)
{
    const int i = blockIdx.x * 256 + threadIdx.x;
    if (i < WQ_ROWS * WK) {
        const int r = i / WK, c = i % WK;
        const float v = (r < 540 && c < 180) ? qkv_w[r * 180 + c] : 0.f;
        wq[i] = f2bf(v);
    }
    const int j = i - WQ_ROWS * WK;
    if (j >= 0 && j < 192 * WK) {
        const int r = j / WK, c = j % WK;
        const float v = (r < 180 && c < 180) ? proj_w[r * 180 + c] : 0.f;
        wp[j] = f2bf(v);
    }
}

__global__ void __launch_bounds__(NT, 1)
waga_mfma(const float* __restrict__ x,
          const float* __restrict__ bpe,
          const unsigned short* __restrict__ wq,
          const unsigned short* __restrict__ wp,
          const float* __restrict__ qkv_b,
          const float* __restrict__ proj_b,
          const float* __restrict__ tau,
          float* __restrict__ out)
{
    extern __shared__ char smem[];
    unsigned short* xb    = (unsigned short*)(smem + OFF_XB);   // also att
    unsigned short* q_lds = (unsigned short*)(smem + OFF_Q);
    unsigned short* k_lds = (unsigned short*)(smem + OFF_K);
    unsigned short* vT    = (unsigned short*)(smem + OFF_VT);
    float*          dBs   = (float*)(smem + OFF_DB);
    float*          S_lds = (float*)(smem + OFF_S);
    float*          bpes  = (float*)(smem + OFF_S);             // alias (dead before S used)
    unsigned short* P_lds = (unsigned short*)(smem + OFF_P);
    float*          ostage= (float*)(smem + OFF_OST);
    unsigned short* att   = xb;

    const int b = blockIdx.x;
    const int t = threadIdx.x;
    const int w = t >> 6;        // wave 0..7
    const int l = t & 63;
    const int lr = l & 15;       // row/col within tile
    const int g  = l >> 4;       // k-group 0..3

    // ---- zero all LDS (pads must be 0 for MFMA K-padding) ----
    {
        f32x4 z = {0.f, 0.f, 0.f, 0.f};
        f32x4* p = (f32x4*)smem;
        for (int i = t; i < LDS_BYTES / 16; i += NT) p[i] = z;
    }
    __syncthreads();

    // ---- stage x -> bf16 xb[64][200], bpe -> bpes[64][20] ----
    {
        const float* xw = x + (size_t)b * (64 * 180);
        for (int i = t; i < 64 * 45; i += NT) {
            const int n = i / 45, c4 = i % 45;
            const float4 v = *reinterpret_cast<const float4*>(xw + i * 4);
            unsigned short* d = xb + n * XB_P + c4 * 4;
            d[0] = f2bf(v.x); d[1] = f2bf(v.y); d[2] = f2bf(v.z); d[3] = f2bf(v.w);
        }
        const float* bw = bpe + (size_t)b * (64 * 16);
        for (int i = t; i < 64 * 4; i += NT) {
            const int n = i / 4, k4 = i % 4;
            const float4 v = *reinterpret_cast<const float4*>(bw + i * 4);
            float* d = bpes + n * 20 + 4 * k4;
            d[0] = v.x; d[1] = v.y; d[2] = v.z; d[3] = v.w;
        }
    }
    __syncthreads();

    // ---- dB[i][j] = ||bpe_i - bpe_j|| (fp32 VALU) ----
    {
        const int ti = t >> 4, tj = t & 15;
        float acc[2][4] = {{0.f,0.f,0.f,0.f},{0.f,0.f,0.f,0.f}};
        #pragma unroll
        for (int k4 = 0; k4 < 4; ++k4) {
            const float4 a0 = *reinterpret_cast<const float4*>(bpes + ti * 20 + 4 * k4);
            const float4 a1 = *reinterpret_cast<const float4*>(bpes + (ti + 32) * 20 + 4 * k4);
            #pragma unroll
            for (int e = 0; e < 4; ++e) {
                const float4 bb = *reinterpret_cast<const float4*>(bpes + (tj + 16 * e) * 20 + 4 * k4);
                float d;
                d = a0.x - bb.x; acc[0][e] += d * d;
                d = a0.y - bb.y; acc[0][e] += d * d;
                d = a0.z - bb.z; acc[0][e] += d * d;
                d = a0.w - bb.w; acc[0][e] += d * d;
                d = a1.x - bb.x; acc[1][e] += d * d;
                d = a1.y - bb.y; acc[1][e] += d * d;
                d = a1.z - bb.z; acc[1][e] += d * d;
                d = a1.w - bb.w; acc[1][e] += d * d;
            }
        }
        #pragma unroll
        for (int r = 0; r < 2; ++r)
            #pragma unroll
            for (int e = 0; e < 4; ++e)
                dBs[(ti + 32 * r) * DB_P + tj + 16 * e] = sqrtf(acc[r][e]);
    }

    // ---- QKV GEMM: [64 tok] x [540 ch], K=192. quads of N-tiles per wave ----
    {
        const int ntbase = 4 * w;          // nt 0..31 in quads
        f32x4 acc[4][4];                   // [q][mt]
        #pragma unroll
        for (int q = 0; q < 4; ++q) {
            const int m = (ntbase + q) * 16 + lr;
            const float bias = (m < 540) ? qkv_b[m] : 0.f;
            #pragma unroll
            for (int mt = 0; mt < 4; ++mt) {
                acc[q][mt][0] = bias; acc[q][mt][1] = bias;
                acc[q][mt][2] = bias; acc[q][mt][3] = bias;
            }
        }
        for (int kk = 0; kk < 6; ++kk) {
            short8b bfr[4];
            #pragma unroll
            for (int q = 0; q < 4; ++q)
                bfr[q] = *reinterpret_cast<const short8b*>(wq + ((ntbase + q) * 16 + lr) * WK + kk * 32 + g * 8);
            #pragma unroll
            for (int mt = 0; mt < 4; ++mt) {
                const short8b af = *reinterpret_cast<const short8b*>(xb + (mt * 16 + lr) * XB_P + kk * 32 + g * 8);
                #pragma unroll
                for (int q = 0; q < 4; ++q)
                    acc[q][mt] = __builtin_amdgcn_mfma_f32_16x16x32_bf16(af, bfr[q], acc[q][mt], 0, 0, 0);
            }
        }
        #pragma unroll
        for (int q = 0; q < 4; ++q) {
            const int m = (ntbase + q) * 16 + lr;
            if (m < 540) {
                const int which = m / 180, mm = m % 180, hh = mm / 30, dd = mm % 30;
                unsigned short* dst; int ts; float sc;
                if (which == 0)      { dst = q_lds + hh * 2560 + dd;      ts = QK_P; sc = SCALE; }
                else if (which == 1) { dst = k_lds + hh * 2560 + dd;      ts = QK_P; sc = 1.f; }
                else                 { dst = vT + hh * 2304 + dd * VT_P;  ts = 1;    sc = 1.f; }
                #pragma unroll
                for (int mt = 0; mt < 4; ++mt)
                    #pragma unroll
                    for (int i = 0; i < 4; ++i) {
                        const int tok = mt * 16 + g * 4 + i;
                        dst[tok * ts] = f2bf(acc[q][mt][i] * sc);
                    }
            }
        }
        // tail: nt 32,33 on waves 6,7
        if (w >= 6) {
            const int nt = 26 + w;
            const int m = nt * 16 + lr;
            f32x4 acc2[4];
            const float bias = (m < 540) ? qkv_b[m] : 0.f;
            #pragma unroll
            for (int mt = 0; mt < 4; ++mt) {
                acc2[mt][0] = bias; acc2[mt][1] = bias; acc2[mt][2] = bias; acc2[mt][3] = bias;
            }
            for (int kk = 0; kk < 6; ++kk) {
                const short8b bf = *reinterpret_cast<const short8b*>(wq + m * WK + kk * 32 + g * 8);
                #pragma unroll
                for (int mt = 0; mt < 4; ++mt) {
                    const short8b af = *reinterpret_cast<const short8b*>(xb + (mt * 16 + lr) * XB_P + kk * 32 + g * 8);
                    acc2[mt] = __builtin_amdgcn_mfma_f32_16x16x32_bf16(af, bf, acc2[mt], 0, 0, 0);
                }
            }
            if (m < 540) {
                const int which = m / 180, mm = m % 180, hh = mm / 30, dd = mm % 30;
                unsigned short* dst; int ts; float sc;
                if (which == 0)      { dst = q_lds + hh * 2560 + dd;      ts = QK_P; sc = SCALE; }
                else if (which == 1) { dst = k_lds + hh * 2560 + dd;      ts = QK_P; sc = 1.f; }
                else                 { dst = vT + hh * 2304 + dd * VT_P;  ts = 1;    sc = 1.f; }
                #pragma unroll
                for (int mt = 0; mt < 4; ++mt)
                    #pragma unroll
                    for (int i = 0; i < 4; ++i) {
                        const int tok = mt * 16 + g * 4 + i;
                        dst[tok * ts] = f2bf(acc2[mt][i] * sc);
                    }
            }
        }
    }
    __syncthreads();

    // ---- per-head attention ----
    for (int h = 0; h < 6; ++h) {
        const float it = 1.f / fmaxf(tau[h], 1e-6f);
        // S = q k^T with C-init = -dB/tau  (16 tiles, 2 per wave)
        for (int tid = w; tid < 16; tid += 8) {
            const int mt = tid >> 2, nt2 = tid & 3;
            f32x4 acc;
            #pragma unroll
            for (int i = 0; i < 4; ++i)
                acc[i] = -dBs[(mt * 16 + g * 4 + i) * DB_P + nt2 * 16 + lr] * it;
            const short8b af = *reinterpret_cast<const short8b*>(q_lds + h * 2560 + (mt * 16 + lr) * QK_P + g * 8);
            const short8b bf = *reinterpret_cast<const short8b*>(k_lds + h * 2560 + (nt2 * 16 + lr) * QK_P + g * 8);
            acc = __builtin_amdgcn_mfma_f32_16x16x32_bf16(af, bf, acc, 0, 0, 0);
            #pragma unroll
            for (int i = 0; i < 4; ++i)
                S_lds[(mt * 16 + g * 4 + i) * S_P + nt2 * 16 + lr] = acc[i];
        }
        __syncthreads();

        // softmax rows -> P (bf16)
        {
            const int tn = t >> 4, tj = t & 15;
            #pragma unroll
            for (int r = 0; r < 2; ++r) {
                const int row = tn + 32 * r;
                float s0 = S_lds[row * S_P + tj];
                float s1 = S_lds[row * S_P + tj + 16];
                float s2 = S_lds[row * S_P + tj + 32];
                float s3 = S_lds[row * S_P + tj + 48];
                float mx = fmaxf(fmaxf(s0, s1), fmaxf(s2, s3));
                #pragma unroll
                for (int o = 1; o < 16; o <<= 1) mx = fmaxf(mx, __shfl_xor(mx, o, 16));
                float p0 = __expf(s0 - mx), p1 = __expf(s1 - mx);
                float p2 = __expf(s2 - mx), p3 = __expf(s3 - mx);
                float sum = p0 + p1 + p2 + p3;
                #pragma unroll
                for (int o = 1; o < 16; o <<= 1) sum += __shfl_xor(sum, o, 16);
                const float inv = 1.f / sum;
                P_lds[row * PP_P + tj]      = f2bf(p0 * inv);
                P_lds[row * PP_P + tj + 16] = f2bf(p1 * inv);
                P_lds[row * PP_P + tj + 32] = f2bf(p2 * inv);
                P_lds[row * PP_P + tj + 48] = f2bf(p3 * inv);
            }
        }
        __syncthreads();

        // PV: [64 tok] x [30 dd], K = 64.  1 tile per wave.
        {
            const int mt = w >> 1, nt2 = w & 1;
            f32x4 acc = {0.f, 0.f, 0.f, 0.f};
            #pragma unroll
            for (int ks = 0; ks < 2; ++ks) {
                const short8b af = *reinterpret_cast<const short8b*>(P_lds + (mt * 16 + lr) * PP_P + ks * 32 + g * 8);
                const short8b bf = *reinterpret_cast<const short8b*>(vT + h * 2304 + (nt2 * 16 + lr) * VT_P + ks * 32 + g * 8);
                acc = __builtin_amdgcn_mfma_f32_16x16x32_bf16(af, bf, acc, 0, 0, 0);
            }
            const int dd = nt2 * 16 + lr;
            if (dd < 30) {
                #pragma unroll
                for (int i = 0; i < 4; ++i)
                    att[(mt * 16 + g * 4 + i) * XB_P + h * 30 + dd] = f2bf(acc[i]);
            }
        }
        __syncthreads();
    }

    // ---- proj: [64 tok] x [180], K=192 ----
    {
        for (int nt = w; nt < 12; nt += 8) {
            f32x4 acc[4];
            #pragma unroll
            for (int mt = 0; mt < 4; ++mt) { acc[mt][0]=0.f; acc[mt][1]=0.f; acc[mt][2]=0.f; acc[mt][3]=0.f; }
            for (int kk = 0; kk < 6; ++kk) {
                const short8b bf = *reinterpret_cast<const short8b*>(wp + (nt * 16 + lr) * WK + kk * 32 + g * 8);
                #pragma unroll
                for (int mt = 0; mt < 4; ++mt) {
                    const short8b af = *reinterpret_cast<const short8b*>(att + (mt * 16 + lr) * XB_P + kk * 32 + g * 8);
                    acc[mt] = __builtin_amdgcn_mfma_f32_16x16x32_bf16(af, bf, acc[mt], 0, 0, 0);
                }
            }
            const int mcol = nt * 16 + lr;
            if (mcol < 180) {
                const float pb = proj_b[mcol];
                #pragma unroll
                for (int mt = 0; mt < 4; ++mt)
                    #pragma unroll
                    for (int i = 0; i < 4; ++i)
                        ostage[(mt * 16 + g * 4 + i) * OST_P + mcol] = acc[mt][i] + pb;
            }
        }
    }
    __syncthreads();

    // ---- coalesced output dump ----
    {
        float4* src = (float4*)ostage;
        float4* dst = (float4*)(out + (size_t)b * (64 * 180));
        for (int i = t; i < 64 * 180 / 4; i += NT) dst[i] = src[i];
    }
}

extern "C" void kernel_launch(void* const* d_in, const int* in_sizes, int n_in,
                              void* d_out, int out_size, void* d_ws, size_t ws_size,
                              hipStream_t stream) {
    (void)in_sizes; (void)n_in; (void)out_size; (void)ws_size;
    const float* x      = (const float*)d_in[0];
    const float* bpe    = (const float*)d_in[1];
    const float* qkv_w  = (const float*)d_in[2];
    const float* qkv_b  = (const float*)d_in[3];
    const float* proj_w = (const float*)d_in[4];
    const float* proj_b = (const float*)d_in[5];
    const float* tau    = (const float*)d_in[6];

    unsigned short* wq = (unsigned short*)d_ws;                    // 544*192 bf16
    unsigned short* wp = wq + WQ_ROWS * WK;                        // 192*192 bf16

    prep_weights<<<(WQ_ROWS * WK + 192 * WK + 255) / 256, 256, 0, stream>>>(qkv_w, proj_w, wq, wp);

    (void)hipFuncSetAttribute((const void*)waga_mfma,
                              hipFuncAttributeMaxDynamicSharedMemorySize,
                              LDS_BYTES);
    waga_mfma<<<NWIN, NT, LDS_BYTES, stream>>>(x, bpe, wq, wp, qkv_b, proj_b, tau,
                                               (float*)d_out);
}

// Round 3
// 775.527 us; speedup vs baseline: 8.9187x; 1.0856x over previous
//
#include <hip/hip_runtime.h>
#include <math.h>

typedef __attribute__((ext_vector_type(8))) short short8b;          // 8 bf16
typedef __attribute__((ext_vector_type(4))) float f32x4;            // MFMA acc
typedef __attribute__((ext_vector_type(4))) unsigned short ushort4b;
typedef __attribute__((ext_vector_type(2))) unsigned short ushort2b;

#define NWIN 8192
#define NT   1024
#define SCALE 0.18257418583505536f   // 30^-0.5

// ---- LDS geometry (element pitches) ----
#define XB_P  200   // xb/att [64][200] bf16, cols 180..199 zero   (row 400B, bank step 4 -> free)
#define QK_P  392   // qk [64][392] bf16: per head h: q at h*64, k at h*64+32 (row 784B, step 4)
#define VT_P  72    // vT per head [32][72] bf16 (row 144B, step 4)
#define DB_P  66    // dB [64][66] f32 (4-row step 8 -> 2-way)
#define SCR_P 80    // per-wave P scratch [16][80] bf16 (write-free banking)
#define OST_P 180   // out staging [64][180] f32

// ---- LDS offsets (bytes) ----
#define OFF_XB  0                     // 25600
#define OFF_QK  25600                 // 64*392*2 = 50176
#define OFF_VT  75776                 // 6*32*72*2 = 27648
#define OFF_DB  103424                // 64*66*4 = 16896
#define OFF_SCR 120320                // 16*16*80*2 = 40960
#define LDS_BYTES 161280              // <= 163840
#define OFF_OST OFF_QK                // 46080 <= 50176 (qk dead after S)
#define OFF_BPE OFF_SCR               // 5120  <= 40960 (bpes dead before scr used)

#define WQ_ROWS 544
#define WK 192

__device__ __forceinline__ unsigned short f2bf(float f) {
    union { float f; unsigned int u; } v; v.f = f;
    return (unsigned short)((v.u + 0x7FFFu + ((v.u >> 16) & 1u)) >> 16);
}

__global__ void prep_weights(const float* __restrict__ qkv_w,
                             const float* __restrict__ proj_w,
                             unsigned short* __restrict__ wq,
                             unsigned short* __restrict__ wp)
{
    const int i = blockIdx.x * 256 + threadIdx.x;
    if (i < WQ_ROWS * WK) {
        const int r = i / WK, c = i % WK;
        wq[i] = f2bf((r < 540 && c < 180) ? qkv_w[r * 180 + c] : 0.f);
    }
    const int j = i - WQ_ROWS * WK;
    if (j >= 0 && j < 192 * WK) {
        const int r = j / WK, c = j % WK;
        wp[j] = f2bf((r < 180 && c < 180) ? proj_w[r * 180 + c] : 0.f);
    }
}

__global__ void __launch_bounds__(NT, 4)
waga_mfma(const float* __restrict__ x,
          const float* __restrict__ bpe,
          const unsigned short* __restrict__ wq,
          const unsigned short* __restrict__ wp,
          const float* __restrict__ qkv_b,
          const float* __restrict__ proj_b,
          const float* __restrict__ tau,
          float* __restrict__ out)
{
    extern __shared__ char smem[];
    unsigned short* xb   = (unsigned short*)(smem + OFF_XB);   // aliased by att
    unsigned short* qk   = (unsigned short*)(smem + OFF_QK);   // aliased by ostage
    unsigned short* vT   = (unsigned short*)(smem + OFF_VT);
    float*          dBs  = (float*)(smem + OFF_DB);
    unsigned short* scr  = (unsigned short*)(smem + OFF_SCR);  // per-wave P bounce
    float*          bpes = (float*)(smem + OFF_BPE);           // alias over scr
    unsigned short* att  = xb;
    float*          ostage = (float*)(smem + OFF_OST);

    const int b = blockIdx.x;
    const int t = threadIdx.x;
    const int w = t >> 6;      // wave 0..15
    const int l = t & 63;
    const int lr = l & 15;     // row/col within 16-tile
    const int g  = l >> 4;     // k-group 0..3

    // ================= phase 1: pad-zero + stage =================
    // xb pad cols 180..199 (also serves att pads read by proj K up to 191)
    if (t < 320) {                       // 64 rows x 5 ushort4 chunks
        const int n = t / 5, c = t % 5;
        ushort4b z = {0, 0, 0, 0};
        *reinterpret_cast<ushort4b*>(xb + n * XB_P + 180 + 4 * c) = z;
    }
    // qk pad cols 30,31 / 62,63 of each head slice (read by S-MFMA K=32)
    if (t < 768) {                       // 64 tok x 6 h x 2 (q,k)
        const int tok = t / 12, r = t % 12;
        const int col = (r >> 1) * 64 + (r & 1) * 32 + 30;
        ushort2b z2 = {0, 0};
        *reinterpret_cast<ushort2b*>(qk + tok * QK_P + col) = z2;
    }
    // stage x -> bf16 xb
    {
        const float* xw = x + (size_t)b * (64 * 180);
        for (int i = t; i < 64 * 45; i += NT) {
            const int n = i / 45, c4 = i % 45;
            const float4 v = *reinterpret_cast<const float4*>(xw + i * 4);
            ushort4b o;
            o[0] = f2bf(v.x); o[1] = f2bf(v.y); o[2] = f2bf(v.z); o[3] = f2bf(v.w);
            *reinterpret_cast<ushort4b*>(xb + n * XB_P + c4 * 4) = o;
        }
    }
    // stage bpe (f32)
    if (t < 256) {
        const float* bw = bpe + (size_t)b * (64 * 16);
        const int n = t >> 2, k4 = t & 3;
        const float4 v = *reinterpret_cast<const float4*>(bw + t * 4);
        *reinterpret_cast<float4*>(bpes + n * 20 + 4 * k4) = v;
    }
    __syncthreads();

    // ================= phase 2: dB (VALU) + QKV GEMM =================
    {   // dB[i][j] = ||bpe_i - bpe_j||; thread -> row ti, cols tj+16e
        const int ti = t >> 4, tj = t & 15;
        float acc[4] = {0.f, 0.f, 0.f, 0.f};
        #pragma unroll
        for (int k4 = 0; k4 < 4; ++k4) {
            const float4 a = *reinterpret_cast<const float4*>(bpes + ti * 20 + 4 * k4);
            #pragma unroll
            for (int e = 0; e < 4; ++e) {
                const float4 bb = *reinterpret_cast<const float4*>(bpes + (tj + 16 * e) * 20 + 4 * k4);
                float d;
                d = a.x - bb.x; acc[e] += d * d;
                d = a.y - bb.y; acc[e] += d * d;
                d = a.z - bb.z; acc[e] += d * d;
                d = a.w - bb.w; acc[e] += d * d;
            }
        }
        #pragma unroll
        for (int e = 0; e < 4; ++e)
            dBs[ti * DB_P + tj + 16 * e] = sqrtf(acc[e]);
    }

    {   // QKV: 34 n-tiles over 16 waves: nt = {w, w+16, (w<2: 32+w)}
        const int nt0 = w, nt1 = w + 16, nt2q = 32 + w;
        const bool has2 = (w < 2);
        const int m0 = nt0 * 16 + lr, m1 = nt1 * 16 + lr, m2 = nt2q * 16 + lr;
        f32x4 acc0[4], acc1[4], acc2[4];
        const float b0 = (m0 < 540) ? qkv_b[m0] : 0.f;
        const float b1 = (m1 < 540) ? qkv_b[m1] : 0.f;
        const float b2 = (has2 && m2 < 540) ? qkv_b[m2] : 0.f;
        #pragma unroll
        for (int mt = 0; mt < 4; ++mt) {
            #pragma unroll
            for (int i = 0; i < 4; ++i) { acc0[mt][i] = b0; acc1[mt][i] = b1; acc2[mt][i] = b2; }
        }
        for (int kk = 0; kk < 6; ++kk) {
            short8b af[4];
            #pragma unroll
            for (int mt = 0; mt < 4; ++mt)
                af[mt] = *reinterpret_cast<const short8b*>(xb + (mt * 16 + lr) * XB_P + kk * 32 + g * 8);
            const short8b bf0 = *reinterpret_cast<const short8b*>(wq + (size_t)m0 * WK + kk * 32 + g * 8);
            #pragma unroll
            for (int mt = 0; mt < 4; ++mt)
                acc0[mt] = __builtin_amdgcn_mfma_f32_16x16x32_bf16(af[mt], bf0, acc0[mt], 0, 0, 0);
            const short8b bf1 = *reinterpret_cast<const short8b*>(wq + (size_t)m1 * WK + kk * 32 + g * 8);
            #pragma unroll
            for (int mt = 0; mt < 4; ++mt)
                acc1[mt] = __builtin_amdgcn_mfma_f32_16x16x32_bf16(af[mt], bf1, acc1[mt], 0, 0, 0);
            if (has2) {
                const short8b bf2 = *reinterpret_cast<const short8b*>(wq + (size_t)m2 * WK + kk * 32 + g * 8);
                #pragma unroll
                for (int mt = 0; mt < 4; ++mt)
                    acc2[mt] = __builtin_amdgcn_mfma_f32_16x16x32_bf16(af[mt], bf2, acc2[mt], 0, 0, 0);
            }
        }
        auto epi = [&](int m, f32x4* acc) {
            if (m < 540) {
                const int which = m / 180, mm = m % 180, hh = mm / 30, dd = mm % 30;
                #pragma unroll
                for (int mt = 0; mt < 4; ++mt)
                    #pragma unroll
                    for (int i = 0; i < 4; ++i) {
                        const int tok = mt * 16 + g * 4 + i;
                        const float v = acc[mt][i];
                        if (which == 0)      qk[tok * QK_P + hh * 64 + dd] = f2bf(v * SCALE);
                        else if (which == 1) qk[tok * QK_P + hh * 64 + 32 + dd] = f2bf(v);
                        else                 vT[hh * 2304 + dd * VT_P + tok] = f2bf(v);
                    }
            }
        };
        epi(m0, acc0);
        epi(m1, acc1);
        if (has2) epi(m2, acc2);
    }
    __syncthreads();

    // ================= phase 3: fused attention, all heads =================
    // 24 units (h,mt) over 16 waves; softmax in-register; P via per-wave scratch
    {
        unsigned short* myscr = scr + w * (16 * SCR_P);
        for (int u = w; u < 24; u += 16) {
            const int h = u >> 2, mt = u & 3;
            const float it = 1.f / fmaxf(tau[h], 1e-6f);
            // S tiles: C-init = -dB/tau, one K=32 MFMA per nt2
            f32x4 s[4];
            #pragma unroll
            for (int nt2 = 0; nt2 < 4; ++nt2)
                #pragma unroll
                for (int i = 0; i < 4; ++i)
                    s[nt2][i] = -dBs[(mt * 16 + g * 4 + i) * DB_P + nt2 * 16 + lr] * it;
            const short8b qa = *reinterpret_cast<const short8b*>(qk + (mt * 16 + lr) * QK_P + h * 64 + g * 8);
            #pragma unroll
            for (int nt2 = 0; nt2 < 4; ++nt2) {
                const short8b kb = *reinterpret_cast<const short8b*>(qk + (nt2 * 16 + lr) * QK_P + h * 64 + 32 + g * 8);
                s[nt2] = __builtin_amdgcn_mfma_f32_16x16x32_bf16(qa, kb, s[nt2], 0, 0, 0);
            }
            // in-register softmax: row r = g*4+i spans 4 regs x 16 lanes
            float mx[4], sm[4];
            #pragma unroll
            for (int i = 0; i < 4; ++i)
                mx[i] = fmaxf(fmaxf(s[0][i], s[1][i]), fmaxf(s[2][i], s[3][i]));
            #pragma unroll
            for (int o = 1; o < 16; o <<= 1)
                #pragma unroll
                for (int i = 0; i < 4; ++i)
                    mx[i] = fmaxf(mx[i], __shfl_xor(mx[i], o, 16));
            #pragma unroll
            for (int i = 0; i < 4; ++i) sm[i] = 0.f;
            #pragma unroll
            for (int nt2 = 0; nt2 < 4; ++nt2)
                #pragma unroll
                for (int i = 0; i < 4; ++i) {
                    const float p = __expf(s[nt2][i] - mx[i]);
                    s[nt2][i] = p; sm[i] += p;
                }
            #pragma unroll
            for (int o = 1; o < 16; o <<= 1)
                #pragma unroll
                for (int i = 0; i < 4; ++i)
                    sm[i] += __shfl_xor(sm[i], o, 16);
            #pragma unroll
            for (int i = 0; i < 4; ++i) sm[i] = 1.f / sm[i];
            // bounce P through per-wave scratch (transpose D-layout -> row-major)
            #pragma unroll
            for (int nt2 = 0; nt2 < 4; ++nt2)
                #pragma unroll
                for (int i = 0; i < 4; ++i)
                    myscr[(g * 4 + i) * SCR_P + nt2 * 16 + lr] = f2bf(s[nt2][i] * sm[i]);
            // PV: D[tok][dd], K=64
            f32x4 o0 = {0.f, 0.f, 0.f, 0.f}, o1 = {0.f, 0.f, 0.f, 0.f};
            #pragma unroll
            for (int ks = 0; ks < 2; ++ks) {
                const short8b pa = *reinterpret_cast<const short8b*>(myscr + lr * SCR_P + ks * 32 + g * 8);
                const short8b v0 = *reinterpret_cast<const short8b*>(vT + h * 2304 + lr * VT_P + ks * 32 + g * 8);
                const short8b v1 = *reinterpret_cast<const short8b*>(vT + h * 2304 + (16 + lr) * VT_P + ks * 32 + g * 8);
                o0 = __builtin_amdgcn_mfma_f32_16x16x32_bf16(pa, v0, o0, 0, 0, 0);
                o1 = __builtin_amdgcn_mfma_f32_16x16x32_bf16(pa, v1, o1, 0, 0, 0);
            }
            #pragma unroll
            for (int i = 0; i < 4; ++i) {
                const int tok = mt * 16 + g * 4 + i;
                att[tok * XB_P + h * 30 + lr] = f2bf(o0[i]);           // dd = lr < 16
                if (lr < 14)
                    att[tok * XB_P + h * 30 + 16 + lr] = f2bf(o1[i]);  // dd = 16+lr < 30
            }
        }
    }
    __syncthreads();

    // ================= phase 4: output projection =================
    {
        for (int tid = 3 * w; tid < 3 * w + 3; ++tid) {   // 48 tiles: (nt, mt)
            const int nt = tid >> 2, mt = tid & 3;
            f32x4 acc = {0.f, 0.f, 0.f, 0.f};
            for (int kk = 0; kk < 6; ++kk) {
                const short8b af = *reinterpret_cast<const short8b*>(att + (mt * 16 + lr) * XB_P + kk * 32 + g * 8);
                const short8b bf = *reinterpret_cast<const short8b*>(wp + (nt * 16 + lr) * WK + kk * 32 + g * 8);
                acc = __builtin_amdgcn_mfma_f32_16x16x32_bf16(af, bf, acc, 0, 0, 0);
            }
            const int mcol = nt * 16 + lr;
            if (mcol < 180) {
                const float pb = proj_b[mcol];
                #pragma unroll
                for (int i = 0; i < 4; ++i)
                    ostage[(mt * 16 + g * 4 + i) * OST_P + mcol] = acc[i] + pb;
            }
        }
    }
    __syncthreads();

    // ================= phase 5: coalesced dump =================
    {
        const float4* src = (const float4*)ostage;
        float4* dst = (float4*)(out + (size_t)b * (64 * 180));
        for (int i = t; i < 64 * 180 / 4; i += NT) dst[i] = src[i];
    }
}

extern "C" void kernel_launch(void* const* d_in, const int* in_sizes, int n_in,
                              void* d_out, int out_size, void* d_ws, size_t ws_size,
                              hipStream_t stream) {
    (void)in_sizes; (void)n_in; (void)out_size; (void)ws_size;
    const float* x      = (const float*)d_in[0];
    const float* bpe    = (const float*)d_in[1];
    const float* qkv_w  = (const float*)d_in[2];
    const float* qkv_b  = (const float*)d_in[3];
    const float* proj_w = (const float*)d_in[4];
    const float* proj_b = (const float*)d_in[5];
    const float* tau    = (const float*)d_in[6];

    unsigned short* wq = (unsigned short*)d_ws;        // 544*192 bf16
    unsigned short* wp = wq + WQ_ROWS * WK;            // 192*192 bf16

    prep_weights<<<(WQ_ROWS * WK + 192 * WK + 255) / 256, 256, 0, stream>>>(qkv_w, proj_w, wq, wp);

    (void)hipFuncSetAttribute((const void*)waga_mfma,
                              hipFuncAttributeMaxDynamicSharedMemorySize,
                              LDS_BYTES);
    waga_mfma<<<NWIN, NT, LDS_BYTES, stream>>>(x, bpe, wq, wp, qkv_b, proj_b, tau,
                                               (float*)d_out);
}